// Round 13
// baseline (275.196 us; speedup 1.0000x reference)
//
#include <hip/hip_runtime.h>

// Problem constants
#define B_DIM   4096
#define C_DIM   128
#define TOPK    8
#define K_INST  16
#define P_IDS   256          // B/K_INST
#define N_DIM   32768        // B*TOPK
#define INV_TEMP 20.0f       // 1/0.05
#define EPS 1e-6f
#define TSZ 16384            // u16 per 32 KB A-tile LDS buffer (128 rows x 128 k)
#define NBLK 512             // persistent grid: 2 blocks/CU x 256 CU, LDS-pinned

#define NA4 131072           // 4096*128/4
#define NTOT4 1179648        // (4096*128 + 32768*128)/4
#define MAGIC1 0x13579BDFu
#define MAGIC2 0x2468ACE1u

typedef unsigned short u16;
typedef __attribute__((ext_vector_type(8))) short bf16x8;
typedef __attribute__((ext_vector_type(16))) float f32x16;

struct alignas(8) U16x4 { u16 x, y, z, w; };

__device__ __forceinline__ u16 f2bf(float x) {
    union { float f; unsigned u; } v; v.f = x;
    unsigned r = v.u + 0x7fffu + ((v.u >> 16) & 1u);   // RTN-even
    return (u16)(r >> 16);
}

__device__ __forceinline__ void gload_lds16(const u16* g, u16* l) {
    __builtin_amdgcn_global_load_lds(
        (__attribute__((address_space(1))) void*)g,
        (__attribute__((address_space(3))) void*)l,
        16, 0, 0);
}

// ---- device-scope grid barrier (persistent kernel, all NBLK co-resident) ----
// Tokens live in d_ws (re-poisoned 0xAA each launch -> known != MAGIC state).
// Writer: __threadfence() + release-store token. Block 0 scans all tokens,
// release-stores go; others acquire-poll go. Release/acquire at AGENT scope
// handles cross-XCD L2 (writeback on release, invalidate on acquire).
__device__ __forceinline__ void grid_barrier(unsigned* tok, unsigned* go,
                                             unsigned magic, int bid, int tid) {
    __threadfence();
    if (tid == 0)
        __hip_atomic_store(&tok[bid], magic, __ATOMIC_RELEASE, __HIP_MEMORY_SCOPE_AGENT);
    if (bid == 0) {
        for (;;) {
            int ok = (__hip_atomic_load(&tok[tid], __ATOMIC_ACQUIRE, __HIP_MEMORY_SCOPE_AGENT) == magic)
                  && (__hip_atomic_load(&tok[tid + 256], __ATOMIC_ACQUIRE, __HIP_MEMORY_SCOPE_AGENT) == magic);
            if (__syncthreads_and(ok)) break;
            __builtin_amdgcn_s_sleep(2);
        }
        if (tid == 0)
            __hip_atomic_store(go, magic, __ATOMIC_RELEASE, __HIP_MEMORY_SCOPE_AGENT);
    } else {
        if (tid == 0)
            while (__hip_atomic_load(go, __ATOMIC_ACQUIRE, __HIP_MEMORY_SCOPE_AGENT) != magic)
                __builtin_amdgcn_s_sleep(2);
    }
    __syncthreads();
}

// ================= single fused persistent kernel =================
// R12 post-mortem: 3 dispatches cost ~20 us EACH in inter-dispatch overhead
// (~70 us total vs ~6 us of convert+phase2 work) — bigger than all remaining
// phase1 headroom. R13 fuses everything into ONE dispatch with two software
// grid barriers. 512 blocks x 256 thr; 64 KB LDS forces exactly 2 blocks/CU,
// so the whole grid is co-resident (barrier-safe).
// Section 2 = R12's proven phase1 (48.5 us, absmax 0): zero-redundancy m-split
// waves, 32x32x16 swapped-operand MFMA, XOR-swizzled DMA staging, partial
// vmcnt drains. Now 32 iters/block over all 4096 rows; B frags loaded ONCE
// (pc-only dependence — halves R12's B prologue).
__global__ __launch_bounds__(256, 2) void fused(const float4* __restrict__ fa,
                                                const float4* __restrict__ fs,
                                                const int*    __restrict__ labels,
                                                float*        __restrict__ out,
                                                u16*   __restrict__ wsA,   // bf16 [4096][128]
                                                u16*   __restrict__ wsS,   // bf16 [32768][128]
                                                float* __restrict__ pmax,  // [512][4096]
                                                float* __restrict__ pmin,  // [2][4096]
                                                unsigned* __restrict__ tokA,
                                                unsigned* __restrict__ tokB,
                                                unsigned* __restrict__ go) {
    __shared__ u16 Als[2 * TSZ];      // 64 KB double buffer (reused by phase2)

    const int tid = threadIdx.x;      // 0..255
    const int bid = blockIdx.x;       // 0..511 == pc (64-col group)

    // ---------- section 1: fp32 -> bf16 convert + out zero ----------
    if (bid == 0 && tid == 0) *out = 0.f;
#pragma unroll 1
    for (int k = 0; k < 9; ++k) {
        const int i = bid * 2304 + k * 256 + tid;
        float4 v;
        u16* dst;
        if (i < NA4) { v = fa[i]; dst = wsA + (size_t)i * 4; }
        else         { int j = i - NA4; v = fs[j]; dst = wsS + (size_t)j * 4; }
        U16x4 o = { f2bf(v.x), f2bf(v.y), f2bf(v.z), f2bf(v.w) };
        *(U16x4*)dst = o;
    }

    grid_barrier(tokA, &go[0], MAGIC1, bid, tid);

    // ---------- section 2: pipelined sim + per-block max/min ----------
    {
        const int lane = tid & 63;
        const int wm   = tid >> 6;    // wave = 32-row group (0..3)
        const int pc   = bid;         // 64-col group (identity p = pc>>1)
        const int m5   = lane & 31;   // operand idx within 32
        const int t    = lane >> 5;   // k-half (0/1)

        // staging: thread stages slots s = j*256+tid (j=0..7); slot s holds
        // chunk (row = s>>4, kc = (s&15)^((s>>4)&7)); kc j-invariant.
        const int skc = (tid & 15) ^ ((tid >> 4) & 7);
        const u16* sbase = wsA + (size_t)(tid >> 4) * C_DIM + skc * 8;

        // prologue: DMA tile 0 -> buf0 (async)
        {
            u16* dst = &Als[tid * 8];
#pragma unroll
            for (int j = 0; j < 8; ++j)
                gload_lds16(sbase + (size_t)j * 16 * C_DIM, dst + j * 2048);
        }

        // B fragments: 16 pure bf16 loads, loaded ONCE (pc-only dependence)
        bf16x8 b[2][8];
#pragma unroll
        for (int nc = 0; nc < 2; ++nc)
#pragma unroll
            for (int kk = 0; kk < 8; ++kk)
                b[nc][kk] = *(const bf16x8*)(wsS + (size_t)(pc * 64 + nc * 32 + m5) * C_DIM + kk * 16 + t * 8);

        const int p     = pc >> 1;
        const int itd   = p >> 3;             // iter holding the anchor rows
        const int wmsel = (p & 7) >> 1;       // wave holding them
        const int hsel  = p & 1;              // 16-row half within the wave's 32
        float* const pmax_w = pmax + (size_t)pc * B_DIM;

        __builtin_amdgcn_s_waitcnt(0);        // prologue DMA + B loads done
        __builtin_amdgcn_s_barrier();

        int lofs = 0;
#pragma unroll 1
        for (int it = 0; it < 32; ++it) {
            if (it < 31) {                    // prefetch tile it+1
                u16* dst = &Als[(lofs ^ TSZ) + tid * 8];
                const u16* src = sbase + (size_t)(it + 1) * 128 * C_DIM;
#pragma unroll
                for (int j = 0; j < 8; ++j)
                    gload_lds16(src + (size_t)j * 16 * C_DIM, dst + j * 2048);
            }

            const int row0 = it * 128;

            // A fragments: 8 ds_read_b128, zero cross-wave redundancy
            bf16x8 a[8];
            {
                const int row = wm * 32 + m5;
#pragma unroll
                for (int kk = 0; kk < 8; ++kk) {
                    const int slot = row * 16 + ((kk * 2 + t) ^ (row & 7));
                    a[kk] = *(const bf16x8*)&Als[lofs + slot * 8];
                }
            }

            // 16 MFMAs (32x32x16), swapped operands: D[n][m] (S^T tile)
            f32x16 acc[2] = {};
#pragma unroll
            for (int kk = 0; kk < 8; ++kk)
#pragma unroll
                for (int nc = 0; nc < 2; ++nc)
                    acc[nc] = __builtin_amdgcn_mfma_f32_32x32x16_bf16(b[nc][kk], a[kk], acc[nc], 0, 0, 0);

            // epilogue: per-A-row max; lane holds col m = m5 -> 31 fmax +
            // shfl_xor(32); lanes 0..31 store 2 exclusive 64B lines.
            {
                float m = acc[0][0];
#pragma unroll
                for (int nc = 0; nc < 2; ++nc)
#pragma unroll
                    for (int rr = 0; rr < 16; ++rr)
                        if (nc || rr) m = fmaxf(m, acc[nc][rr]);
                m = fmaxf(m, __shfl_xor(m, 32, 64));
                if (lane < 32)
                    pmax_w[row0 + wm * 32 + lane] = m;
            }

            // diagonal min (anchor identity's own 16 rows)
            if (it == itd && wm == wmsel) {
                float m = fminf(acc[0][0], acc[0][1]);
#pragma unroll
                for (int nc = 0; nc < 2; ++nc)
#pragma unroll
                    for (int rr = 0; rr < 16; ++rr)
                        if (nc || rr > 1) m = fminf(m, acc[nc][rr]);
                m = fminf(m, __shfl_xor(m, 32, 64));
                if (lane < 32 && (lane >> 4) == hsel)
                    pmin[(size_t)(pc & 1) * B_DIM + p * 16 + (lane & 15)] = m;
            }

            if (it < 31) {
                // drain the 8 prefetch DMAs; newest epilogue store stays in
                // flight. vmcnt=1, expcnt=7, lgkmcnt=15 -> 0xF71.
                __builtin_amdgcn_s_waitcnt(0xF71);
                __builtin_amdgcn_s_barrier();
            }
            lofs ^= TSZ;
        }
    }

    grid_barrier(tokB, &go[1], MAGIC2, bid, tid);

    // ---------- section 3: per-row loss + mean (8 rows per block) ----------
    {
        float* part = (float*)Als;            // reuse LDS: [32][9]
        const int r  = tid & 7;
        const int pg = tid >> 3;              // 0..31, covers 8 p each
        const int row = bid * 8 + r;
        const int pid = labels[row];
        const float* base = pmax + row;
        float s = 0.f;
#pragma unroll
        for (int j = 0; j < 8; ++j) {
            const int p = pg * 8 + j;
            const float v = fmaxf(base[(size_t)(2 * p) * B_DIM],
                                  base[(size_t)(2 * p + 1) * B_DIM]);
            s += (p == pid) ? 0.f : __expf(v * INV_TEMP);
        }
        part[pg * 9 + r] = s;
        __syncthreads();
        if (tid < 8) {
            float neg = 0.f;
#pragma unroll
            for (int j = 0; j < 32; ++j) neg += part[j * 9 + tid];
            const int rw = bid * 8 + tid;
            const float mn  = fminf(pmin[rw], pmin[B_DIM + rw]);
            const float pos = __expf(mn * INV_TEMP);
            float loss = -__logf(pos / (pos + neg + EPS) + EPS);
            loss += __shfl_xor(loss, 1, 64);
            loss += __shfl_xor(loss, 2, 64);
            loss += __shfl_xor(loss, 4, 64);
            if (tid == 0) atomicAdd(out, loss * (1.0f / (float)B_DIM));
        }
    }
}

extern "C" void kernel_launch(void* const* d_in, const int* in_sizes, int n_in,
                              void* d_out, int out_size, void* d_ws, size_t ws_size,
                              hipStream_t stream) {
    const float* feats   = (const float*)d_in[0];   // [4096,128]
    const float* feats_s = (const float*)d_in[1];   // [4096,8,128]
    const int*   labels  = (const int*)d_in[2];     // [4096]
    float* out = (float*)d_out;

    // workspace: bf16 A (1 MB) | bf16 S (8 MB) | pmax (8 MB) | pmin (32 KB) | barrier state
    u16* wsA = (u16*)d_ws;
    u16* wsS = wsA + (size_t)B_DIM * C_DIM;
    float* pmax = (float*)((char*)d_ws + (9u << 20));
    float* pmin = pmax + (size_t)NBLK * B_DIM;
    unsigned* tokA = (unsigned*)(pmin + 2 * B_DIM);
    unsigned* tokB = tokA + NBLK;
    unsigned* go   = tokB + NBLK;

    fused<<<NBLK, 256, 0, stream>>>((const float4*)feats, (const float4*)feats_s,
                                    labels, out, wsA, wsS, pmax, pmin, tokA, tokB, go);
}